// Round 7
// baseline (730.851 us; speedup 1.0000x reference)
//
#include <hip/hip_runtime.h>
#include <math.h>

#define B_SZ 2
#define N_SEQ 2048
#define DM 1024
#define H_HEADS 16
#define DH 64
#define KC 32
#define TOPK 100
#define TQ 16
#define KT 64
#define LCAP 448
#define FCAP 152

typedef _Float16 half2_t __attribute__((ext_vector_type(2)));
typedef _Float16 half4_t __attribute__((ext_vector_type(4)));
typedef _Float16 half8_t __attribute__((ext_vector_type(8)));
typedef float floatx4 __attribute__((ext_vector_type(4)));

// ---------- helpers ----------
__device__ __forceinline__ unsigned short h2us(_Float16 h) {
  unsigned short u; __builtin_memcpy(&u, &h, 2); return u;
}
__device__ __forceinline__ _Float16 us2h(unsigned short u) {
  _Float16 h; __builtin_memcpy(&h, &u, 2); return h;
}
__device__ __forceinline__ unsigned okey16(unsigned short us) {
  return (us & 0x8000u) ? (unsigned)(unsigned short)~us
                        : (unsigned)(us | 0x8000u);
}

// async global->LDS, 16 B per lane; lds_base must be wave-uniform
__device__ __forceinline__ void stage16(const _Float16* g, _Float16* lds_base,
                                        int lane) {
#if __has_builtin(__builtin_amdgcn_global_load_lds)
  __builtin_amdgcn_global_load_lds(
      (const __attribute__((address_space(1))) void*)g,
      (__attribute__((address_space(3))) void*)lds_base, 16, 0, 0);
#else
  *(half8_t*)(lds_base + lane * 8) = *(const half8_t*)g;
#endif
}

// ---------- constants: Riemann-zero weights ----------
__global__ void const_kernel(float* __restrict__ wre, float* __restrict__ wim) {
  __shared__ double g0s;
  const int k = threadIdx.x;  // 32 threads
  const double PI = 3.14159265358979323846;
  const double E_ = 2.71828182845904523536;
  double n = (double)(k + 1);
  double t = 10.0 + 6.0 * n;
  for (int it = 0; it < 60; ++it) {
    double f  = t / (2.0 * PI) * log(t / (2.0 * PI * E_)) - (n - 0.875);
    double fp = log(t / (2.0 * PI)) / (2.0 * PI);
    t = t - f / fp;
  }
  if (k == 0) g0s = t;
  __syncthreads();
  double g = t / g0s;
  double denom = 0.25 + g * g;
  wre[k] = (float)(0.5 / denom);
  wim[k] = (float)(-g / denom);
}

// ---------- RoPE tables ----------
__global__ __launch_bounds__(256) void rope_kernel(float* __restrict__ cosT,
                                                   float* __restrict__ sinT) {
  int idx = blockIdx.x * 256 + threadIdx.x;  // 65536 = 2048*32
  int kk = idx & 31, n = idx >> 5;
  double inv_freq = pow(10000.0, -(double)kk / 32.0);
  double ph = (double)n * inv_freq;
  cosT[idx] = (float)cos(ph);
  sinT[idx] = (float)sin(ph);
}

// ---------- cast x fp32 -> fp16 ----------
__global__ __launch_bounds__(256) void cast_x(const float* __restrict__ x,
                                              _Float16* __restrict__ xh) {
  int idx = blockIdx.x * 256 + threadIdx.x;
  float4 v = ((const float4*)x)[idx];
  half4_t h;
  h[0] = (_Float16)v.x; h[1] = (_Float16)v.y;
  h[2] = (_Float16)v.z; h[3] = (_Float16)v.w;
  ((half4_t*)xh)[idx] = h;
}

// ---------- transpose-cast W (fp32 [k][n]) -> Wt (fp16 [n][k]) ----------
__global__ __launch_bounds__(256) void transpose_cast(
    const float* __restrict__ W0, const float* __restrict__ W1,
    const float* __restrict__ W2, const float* __restrict__ W3,
    _Float16* __restrict__ T0, _Float16* __restrict__ T1,
    _Float16* __restrict__ T2, _Float16* __restrict__ T3) {
  __shared__ float t[64][65];
  const float* W; _Float16* T;
  switch (blockIdx.z) {
    case 0: W = W0; T = T0; break;
    case 1: W = W1; T = T1; break;
    case 2: W = W2; T = T2; break;
    default: W = W3; T = T3; break;
  }
  const int bx = blockIdx.x;  // k block
  const int by = blockIdx.y;  // n block
  const int tid = threadIdx.x;
  const int c = tid & 15, rr = tid >> 4;
#pragma unroll
  for (int i = 0; i < 4; ++i) {
    int k = rr + i * 16;
    float4 v = *(const float4*)(W + (size_t)(bx * 64 + k) * DM + by * 64 + c * 4);
    t[k][c * 4 + 0] = v.x; t[k][c * 4 + 1] = v.y;
    t[k][c * 4 + 2] = v.z; t[k][c * 4 + 3] = v.w;
  }
  __syncthreads();
#pragma unroll
  for (int i = 0; i < 4; ++i) {
    int n = rr + i * 16;
    half4_t h;
    h[0] = (_Float16)t[c * 4 + 0][n];
    h[1] = (_Float16)t[c * 4 + 1][n];
    h[2] = (_Float16)t[c * 4 + 2][n];
    h[3] = (_Float16)t[c * 4 + 3][n];
    *(half4_t*)(T + (size_t)(by * 64 + n) * DM + bx * 64 + c * 4) = h;
  }
}

// ---------- f16 MFMA GEMM: C[M][1024] = A[M][1024] @ Bt[1024][1024]^T ----------
template <typename OutT>
__device__ __forceinline__ void gemm_mfma_body(const _Float16* __restrict__ A,
                                               const _Float16* __restrict__ Bt,
                                               OutT* __restrict__ C) {
  __shared__ _Float16 As[128 * 32];
  __shared__ _Float16 Bs[128 * 32];
  const int tid = threadIdx.x;
  const int wave = tid >> 6, lane = tid & 63;
  const int wm = wave >> 1, wn = wave & 1;
  const int bm = blockIdx.x * 128, bn = blockIdx.y * 128;
  const int lrow = lane >> 2;       // 0..15 within a 16-row segment
  const int lkb = (lane & 3) * 8;   // k element offset of this lane's 16B
  const int l16 = lane & 15, lq = lane >> 4;
  floatx4 acc[4][4] = {};

  for (int k0 = 0; k0 < DM; k0 += 32) {
    __syncthreads();
#pragma unroll
    for (int s2 = 0; s2 < 2; ++s2) {
      const int seg = wave * 2 + s2;  // 16-row segment of the 128-row tile
      stage16(A + (size_t)(bm + seg * 16 + lrow) * DM + k0 + lkb,
              As + seg * 512, lane);
      stage16(Bt + (size_t)(bn + seg * 16 + lrow) * DM + k0 + lkb,
              Bs + seg * 512, lane);
    }
    __syncthreads();
    half8_t af[4], bf[4];
#pragma unroll
    for (int mi = 0; mi < 4; ++mi)
      af[mi] = *(const half8_t*)(As + (wm * 64 + mi * 16 + l16) * 32 + lq * 8);
#pragma unroll
    for (int ni = 0; ni < 4; ++ni)
      bf[ni] = *(const half8_t*)(Bs + (wn * 64 + ni * 16 + l16) * 32 + lq * 8);
#pragma unroll
    for (int mi = 0; mi < 4; ++mi)
#pragma unroll
      for (int ni = 0; ni < 4; ++ni)
        acc[mi][ni] = __builtin_amdgcn_mfma_f32_16x16x32_f16(
            af[mi], bf[ni], acc[mi][ni], 0, 0, 0);
  }
  // epilogue: C/D layout col=lane&15, row=(lane>>4)*4+reg  [m89-verified]
#pragma unroll
  for (int mi = 0; mi < 4; ++mi)
#pragma unroll
    for (int ni = 0; ni < 4; ++ni) {
      const int col = bn + wn * 64 + ni * 16 + l16;
#pragma unroll
      for (int r = 0; r < 4; ++r) {
        const int row = bm + wm * 64 + mi * 16 + lq * 4 + r;
        C[(size_t)row * DM + col] = (OutT)acc[mi][ni][r];
      }
    }
}

__global__ __launch_bounds__(256) void gemm_qkv_mfma(
    const _Float16* __restrict__ xh, const _Float16* __restrict__ Wt0,
    const _Float16* __restrict__ Wt1, const _Float16* __restrict__ Wt2,
    _Float16* __restrict__ q, _Float16* __restrict__ k,
    _Float16* __restrict__ v) {
  const _Float16* Bt; _Float16* C;
  if (blockIdx.z == 0)      { Bt = Wt0; C = q; }
  else if (blockIdx.z == 1) { Bt = Wt1; C = k; }
  else                      { Bt = Wt2; C = v; }
  gemm_mfma_body<_Float16>(xh, Bt, C);
}

__global__ __launch_bounds__(256) void gemm_out_mfma(
    const _Float16* __restrict__ A, const _Float16* __restrict__ Bt,
    float* __restrict__ C) {
  gemm_mfma_body<float>(A, Bt, C);
}

// ---------- RoPE + w-weighting + layout transform -----------------------
// qh16: fp16, pre-scaled by rsqrt(1+n); kth: fp16 pre-scaled by 0.125*sqrt(1+n)
__global__ __launch_bounds__(256) void transform_kernel(
    const _Float16* __restrict__ q, const _Float16* __restrict__ k,
    const _Float16* __restrict__ v, const float* __restrict__ wre,
    const float* __restrict__ wim, const float* __restrict__ cosT,
    const float* __restrict__ sinT, _Float16* __restrict__ qh16,
    _Float16* __restrict__ kth, _Float16* __restrict__ vth) {
  int idx = blockIdx.x * blockDim.x + threadIdx.x;
  int kk = idx & 31;
  int h  = (idx >> 5) & 15;
  int n  = (idx >> 9) & 2047;
  int b  = idx >> 20;

  size_t base_in = ((size_t)(b * N_SEQ + n)) * DM + h * DH;
  float q_re = (float)q[base_in + 2 * kk], q_im = (float)q[base_in + 2 * kk + 1];
  float k_re = (float)k[base_in + 2 * kk], k_im = (float)k[base_in + 2 * kk + 1];

  float cp = cosT[n * 32 + kk], sp = sinT[n * 32 + kk];

  float qt_re = cp * q_re + sp * q_im;
  float qt_im = cp * q_im - sp * q_re;
  float ktr   = cp * k_re + sp * k_im;
  float kti   = cp * k_im - sp * k_re;

  float wr = wre[kk], wi = wim[kk];
  float qh_re = wr * qt_re - wi * qt_im;
  float qh_im = wr * qt_im + wi * qt_re;

  float sj  = 0.125f * sqrtf(1.0f + (float)n);
  float rsq = rsqrtf(1.0f + (float)n);

  size_t base_out = ((size_t)((b * H_HEADS + h) * N_SEQ + n)) * DH;
  qh16[base_out + kk]      = (_Float16)(qh_re * rsq);
  qh16[base_out + 32 + kk] = (_Float16)(qh_im * rsq);
  kth[base_out + kk]      = (_Float16)(ktr * sj);
  kth[base_out + 32 + kk] = (_Float16)(kti * sj);
  vth[base_out + 2 * kk]     = v[base_in + 2 * kk];
  vth[base_out + 2 * kk + 1] = v[base_in + 2 * kk + 1];
}

// ---------- attention: sampled-cut + candidate-list top-k ----------
__global__ __launch_bounds__(256) void attn_kernel(const _Float16* __restrict__ qh16,
                                                   const _Float16* __restrict__ kth,
                                                   const _Float16* __restrict__ vth,
                                                   _Float16* __restrict__ oh) {
  __shared__ __align__(16) _Float16 ktile[KT][76];   // 9.5 KB; aliased by final_
  __shared__ unsigned hist[TQ][128];                 // 8 KB packed 16-bit counts
  __shared__ unsigned list[TQ][LCAP];                // 28 KB candidates (us<<16|j)
  __shared__ float rowm[TQ], rowsum[TQ];
  __shared__ unsigned cnt[TQ], cnt2[TQ], tkA[TQ];
  __shared__ int bhA[TQ], bselA[TQ], kremA[TQ];
  __shared__ unsigned badmaskSh;
  __shared__ int badflag;

  unsigned* final_ = (unsigned*)&ktile[0][0];        // post-sweep alias, FCAP/row

  const int tile = gridDim.x - 1 - blockIdx.x;  // heavy blocks first
  const int bh   = blockIdx.y;                  // 0..31
  const int i0   = tile * TQ;
  const int tid  = threadIdx.x;
  const int wv = tid >> 6, lane = tid & 63;
  const int l16 = lane & 15, lq = lane >> 4;

  const _Float16* kbase = kth + (size_t)bh * N_SEQ * DH;
  const _Float16* vbase = vth + (size_t)bh * N_SEQ * DH;

  // ---- init ----
#pragma unroll
  for (int u = 0; u < 8; ++u) ((unsigned*)hist)[u * 256 + tid] = 0;
  if (tid < TQ) cnt[tid] = 0;

  // ---- A-fragment: row m=l16 -> q row i0+l16 (pre-scaled fp16) ----
  const _Float16* qrow = qh16 + ((size_t)(bh * N_SEQ + i0 + l16)) * DH;
  half8_t af0 = *(const half8_t*)(qrow + lq * 8);
  half8_t af1 = *(const half8_t*)(qrow + 32 + lq * 8);

  const int ntile = (i0 + TQ + KT - 1) / KT;
  auto sweep = [&](int step, auto epi) {
    for (int t = 0; t < ntile; t += step) {
      const int j0 = t * KT;
      __syncthreads();
#pragma unroll
      for (int u = 0; u < 2; ++u) {
        int idx = u * 256 + tid;  // 512 chunks of 8 halves
        int row = idx >> 3, c8 = idx & 7;
        *(half8_t*)&ktile[row][c8 * 8] =
            *(const half8_t*)(kbase + (size_t)(j0 + row) * DH + c8 * 8);
      }
      __syncthreads();
      half8_t bf0 = *(const half8_t*)&ktile[wv * 16 + l16][lq * 8];
      half8_t bf1 = *(const half8_t*)&ktile[wv * 16 + l16][32 + lq * 8];
      floatx4 acc = {};
      acc = __builtin_amdgcn_mfma_f32_16x16x32_f16(af0, bf0, acc, 0, 0, 0);
      acc = __builtin_amdgcn_mfma_f32_16x16x32_f16(af1, bf1, acc, 0, 0, 0);
      const int jc = j0 + wv * 16 + l16;
#pragma unroll
      for (int r = 0; r < 4; ++r) epi(r, lq * 4 + r, jc, acc[r]);
    }
  };

  // ---- pass A: sampled (every 4th tile) hi-byte histogram ----
  sweep(4, [&](int r, int row, int jc, float sc) {
    if (jc <= i0 + row) {
      unsigned short us = h2us((_Float16)sc);
      unsigned hb = okey16(us) >> 8;
      atomicAdd(&hist[row][hb >> 1], 1u << ((hb & 1) * 16));
    }
  });
  __syncthreads();

  // ---- choose per-row cut byte bh_est from sampled counts ----
  if (tid < TQ) {
    const int i_r = i0 + tid, L = i_r + 1;
    int b = 0;
    if (L > TOPK) {
      int samp = 0;
      for (int t = 0; t < ntile; t += 4) {
        int c = i_r + 1 - t * KT;
        if (c > 0) samp += (c > KT ? KT : c);
      }
      float f = (float)samp / (float)L;
      int C = (int)ceilf(f * (100.0f + 180.0f * (1.0f - f)));
      int cum = 0;
      for (b = 255; b >= 1; --b) {
        cum += (int)((hist[tid][b >> 1] >> ((b & 1) * 16)) & 0xffffu);
        if (cum >= C) break;
      }
      if (b < 0) b = 0;
    }
    bhA[tid] = b;
  }
  if (tid == 0) badmaskSh = 0xFFFFu;
  __syncthreads();

  // ---- pass B (+rare retries): collect candidates hi >= bh_est ----
  int attempt = 0;
  while (true) {
    const unsigned bm = badmaskSh;
    int bh4[4];
#pragma unroll
    for (int r = 0; r < 4; ++r) {
      const int row = lq * 4 + r;
      bh4[r] = ((bm >> row) & 1u) ? bhA[row] : 256;  // 256 = row done
    }
    sweep(1, [&](int r, int row, int jc, float sc) {
      if (jc <= i0 + row) {
        unsigned short us = h2us((_Float16)sc);
        int hb = (int)(okey16(us) >> 8);
        if (hb >= bh4[r]) {
          unsigned pos = atomicAdd(&cnt[row], 1u);
          if (pos < LCAP) list[row][pos] = ((unsigned)us << 16) | (unsigned)jc;
        }
      }
    });
    __syncthreads();
    if (tid == 0) badflag = 0;
    __syncthreads();
    if (tid < TQ) {
      const int L = i0 + tid + 1;
      const unsigned c = cnt[tid];
      const bool isbad =
          (c > (unsigned)LCAP) || (L > TOPK && c < (unsigned)TOPK);
      if (isbad && attempt < 3) {
        if (c > (unsigned)LCAP) { if (bhA[tid] < 255) bhA[tid]++; }
        else                    { if (bhA[tid] > 0)   bhA[tid]--; }
        cnt[tid] = 0;
        badflag = 1;
      } else {
        atomicAnd(&badmaskSh, ~(1u << tid));
      }
    }
    __syncthreads();
    if (!badflag) break;
    ++attempt;
  }

  // ---- small-list exact select: pass 1 (hi-byte) + row max ----
#pragma unroll
  for (int u = 0; u < 8; ++u) ((unsigned*)hist)[u * 256 + tid] = 0;
  __syncthreads();
  {
    const int r = tid >> 4, ts = tid & 15;
    const int n = (int)min(cnt[r], (unsigned)LCAP);
    unsigned kmax = 0;
    for (int s = ts; s < n; s += 16) {
      unsigned key = okey16((unsigned short)(list[r][s] >> 16));
      kmax = kmax > key ? kmax : key;
      unsigned hb = key >> 8;
      atomicAdd(&hist[r][hb >> 1], 1u << ((hb & 1) * 16));
    }
#pragma unroll
    for (int g = 1; g <= 8; g <<= 1) {
      unsigned o = (unsigned)__shfl_xor((int)kmax, g);
      kmax = kmax > o ? kmax : o;
    }
    if (ts == 0) {
      unsigned short us = (kmax & 0x8000u) ? (unsigned short)(kmax & 0x7fffu)
                                           : (unsigned short)(~kmax);
      rowm[r] = (float)us2h(us);
    }
  }
  __syncthreads();
  if (tid < TQ) {
    const int L = i0 + tid + 1;
    int bs = -1, kr = 0;
    if (L > TOPK && cnt[tid] >= (unsigned)TOPK) {
      int cum = 0;
      for (int b = 255; b >= 0; --b) {
        int h = (int)((hist[tid][b >> 1] >> ((b & 1) * 16)) & 0xffffu);
        if (cum + h >= TOPK) { bs = b; kr = TOPK - cum; break; }
        cum += h;
      }
    }
    bselA[tid] = bs; kremA[tid] = kr;
  }
  __syncthreads();
#pragma unroll
  for (int u = 0; u < 8; ++u) ((unsigned*)hist)[u * 256 + tid] = 0;
  __syncthreads();
  // ---- pass 2 (lo-byte within boundary bucket) ----
  {
    const int r = tid >> 4, ts = tid & 15;
    const int bs = bselA[r];
    if (bs >= 0) {
      const int n = (int)min(cnt[r], (unsigned)LCAP);
      for (int s = ts; s < n; s += 16) {
        unsigned key = okey16((unsigned short)(list[r][s] >> 16));
        if ((int)(key >> 8) == bs)
          atomicAdd(&hist[r][(key & 255u) >> 1], 1u << ((key & 1) * 16));
      }
    }
  }
  __syncthreads();
  if (tid < TQ) {
    unsigned tk = 0;
    const int bs = bselA[tid];
    if (bs >= 0) {
      int cum = 0, kr = kremA[tid], b = 255;
      for (; b >= 0; --b) {
        int h = (int)((hist[tid][b >> 1] >> ((b & 1) * 16)) & 0xffffu);
        if (cum + h >= kr) break;
        cum += h;
      }
      if (b < 0) b = 0;
      tk = ((unsigned)bs << 8) | (unsigned)b;
    }
    tkA[tid] = tk;
    cnt2[tid] = 0;
  }
  __syncthreads();

  // ---- filter + exp-sum + compact into final_ (aliases dead ktile) ----
  {
    const int r = tid >> 4, ts = tid & 15;
    const unsigned tk = tkA[r];
    const float m = rowm[r];
    const int n = (int)min(cnt[r], (unsigned)LCAP);
    float lsum = 0.f;
    for (int s = ts; s < n; s += 16) {
      unsigned e = list[r][s];
      unsigned short us = (unsigned short)(e >> 16);
      if (okey16(us) >= tk) {
        float p = expf((float)us2h(us) - m);
        lsum += p;
        unsigned pos = atomicAdd(&cnt2[r], 1u);
        if (pos < FCAP) final_[r * FCAP + pos] = e;
      }
    }
#pragma unroll
    for (int g = 1; g <= 8; g <<= 1) lsum += __shfl_xor(lsum, g);
    if (ts == 0) rowsum[r] = lsum;
  }
  __syncthreads();

  // ---- sparse p @ V, one wave per row ----
  for (int rr = wv; rr < TQ; rr += 4) {
    const int n = (int)min(cnt2[rr], (unsigned)FCAP);
    const float m = rowm[rr];
    const float inv = 1.0f / rowsum[rr];
    float acc = 0.f;
    for (int s = 0; s < n; ++s) {
      unsigned e = final_[rr * FCAP + s];
      const int jj = (int)(e & 0xffffu);
      const float p = expf((float)us2h((unsigned short)(e >> 16)) - m);
      acc += p * (float)vbase[(size_t)jj * DH + lane];
    }
    const int b = bh >> 4, h = bh & 15;
    const int i = i0 + rr;
    oh[((size_t)(b * N_SEQ + i)) * DM + h * DH + lane] = (_Float16)(acc * inv);
  }
}

// ---------- launch ----------
extern "C" void kernel_launch(void* const* d_in, const int* in_sizes, int n_in,
                              void* d_out, int out_size, void* d_ws, size_t ws_size,
                              hipStream_t stream) {
  const float* x  = (const float*)d_in[0];
  const float* Wq = (const float*)d_in[1];
  const float* Wk = (const float*)d_in[2];
  const float* Wv = (const float*)d_in[3];
  const float* Wo = (const float*)d_in[4];
  float* out = (float*)d_out;
  char* ws = (char*)d_ws;

  const size_t MAT = (size_t)B_SZ * N_SEQ * DM;  // 4,194,304 elements
  const size_t WSZ = (size_t)DM * DM;            // 1,048,576

  _Float16* qh16 = (_Float16*)ws;                    ws += MAT * 2;
  _Float16* xh   = (_Float16*)ws;                    ws += MAT * 2;
  _Float16* qf   = (_Float16*)ws;                    ws += MAT * 2;
  _Float16* kf   = (_Float16*)ws;                    ws += MAT * 2;
  _Float16* vf   = (_Float16*)ws;                    ws += MAT * 2;
  _Float16* kth  = (_Float16*)ws;                    ws += MAT * 2;
  _Float16* vth  = (_Float16*)ws;                    ws += MAT * 2;
  _Float16* Wt0  = (_Float16*)ws;                    ws += WSZ * 2;
  _Float16* Wt1  = (_Float16*)ws;                    ws += WSZ * 2;
  _Float16* Wt2  = (_Float16*)ws;                    ws += WSZ * 2;
  _Float16* Wt3  = (_Float16*)ws;                    ws += WSZ * 2;
  float*    wre  = (float*)ws;                       ws += KC * 4;
  float*    wim  = (float*)ws;                       ws += KC * 4;
  float*    cosT = (float*)ws;                       ws += (size_t)N_SEQ * KC * 4;
  float*    sinT = (float*)ws;                       ws += (size_t)N_SEQ * KC * 4;
  _Float16* oh   = xh;  // xh dead after QKV GEMM; reuse for attn output

  const_kernel<<<1, 32, 0, stream>>>(wre, wim);
  rope_kernel<<<(N_SEQ * KC) / 256, 256, 0, stream>>>(cosT, sinT);
  cast_x<<<(int)(MAT / 4 / 256), 256, 0, stream>>>(x, xh);
  transpose_cast<<<dim3(16, 16, 4), 256, 0, stream>>>(Wq, Wk, Wv, Wo,
                                                      Wt0, Wt1, Wt2, Wt3);
  gemm_qkv_mfma<<<dim3(32, 8, 3), 256, 0, stream>>>(xh, Wt0, Wt1, Wt2,
                                                    qf, kf, vf);
  transform_kernel<<<(B_SZ * N_SEQ * H_HEADS * KC) / 256, 256, 0, stream>>>(
      qf, kf, vf, wre, wim, cosT, sinT, qh16, kth, vth);
  attn_kernel<<<dim3(N_SEQ / TQ, B_SZ * H_HEADS), 256, 0, stream>>>(
      qh16, kth, vth, oh);
  gemm_out_mfma<<<dim3(32, 8, 1), 256, 0, stream>>>(oh, Wt3, out);
}